// Round 3
// baseline (603.803 us; speedup 1.0000x reference)
//
#include <hip/hip_runtime.h>
#include <hip/hip_bf16.h>
#include <stdint.h>

#define SC 192      // coarse samples (128 + 64)
#define SF 128      // fine (importance) samples
#define NT 192      // threads per block = 3 waves

// z_log coarse grid: seg0 linspace(-1, -1/128, 128) step 1/128; seg1 linspace(0, 1-1/64, 64) step 1/64
__device__ __forceinline__ float zlog_c(int t) {
  return (t < 128) ? (-1.0f + (float)t * 0.0078125f)
                   : ((float)(t - 128) * 0.015625f);
}

__device__ __forceinline__ float delta_c(int t) {
  if (t >= SC - 1) return 0.0f;
  return zlog_c(t + 1) - zlog_c(t);
}

__device__ __forceinline__ float softplus_f(float x) {
  // jax.nn.softplus = max(x,0) + log1p(exp(-|x|))
  return fmaxf(x, 0.0f) + log1pf(expf(-fabsf(x)));
}

// JAX threefry2x32 with key = (0, 42)  [jax.random.key(42): k1=0, k2=42]
__device__ __forceinline__ void threefry2x32_k42(uint32_t& x0, uint32_t& x1) {
  const uint32_t ks0 = 0u, ks1 = 42u;
  const uint32_t ks2 = ks0 ^ ks1 ^ 0x1BD11BDAu;
  const uint32_t ks[3] = {ks0, ks1, ks2};
  const int rot[2][4] = {{13, 15, 26, 6}, {17, 29, 16, 24}};
  x0 += ks[0];
  x1 += ks[1];
#pragma unroll
  for (int i = 0; i < 5; ++i) {
#pragma unroll
    for (int j = 0; j < 4; ++j) {
      x0 += x1;
      const int r = rot[i & 1][j];
      x1 = (x1 << r) | (x1 >> (32 - r));
      x1 ^= x0;
    }
    x0 += ks[(i + 1) % 3];
    x1 += ks[(i + 2) % 3] + (uint32_t)(i + 1);
  }
}

// density MLP: h = relu(x @ Wd1 + bd1); sigma = softplus(h @ Wd2 + bd2)
__device__ __forceinline__ float density_mlp(
    float px, float py, float pz,
    const float* __restrict__ Wd1, const float* __restrict__ bd1,
    const float* __restrict__ Wd2, const float* __restrict__ bd2,
    float* hfeat /*[32]*/) {
  float acc = bd2[0];
#pragma unroll
  for (int k = 0; k < 32; ++k) {
    float v = bd1[k] + px * Wd1[k] + py * Wd1[32 + k] + pz * Wd1[64 + k];
    v = fmaxf(v, 0.0f);
    hfeat[k] = v;
    acc += v * Wd2[k];
  }
  return softplus_f(acc);
}

__global__ __launch_bounds__(NT) void nerf_fwd(
    const float* __restrict__ hh, const float* __restrict__ ww,
    const float* __restrict__ K, const float* __restrict__ E,
    const float* __restrict__ bg,
    const float* __restrict__ Wd1, const float* __restrict__ bd1,
    const float* __restrict__ Wd2, const float* __restrict__ bd2,
    const float* __restrict__ Wc1, const float* __restrict__ bc1,
    const float* __restrict__ Wc2, const float* __restrict__ bc2,
    float* __restrict__ out, int n_rays) {
  const int ray = blockIdx.x;
  const int t = threadIdx.x;

  __shared__ float s_sig[SC];
  __shared__ float s_w[SC];
  __shared__ float s_wre[SC];
  __shared__ float s_cdf[SC];
  __shared__ float s_zlf[SF];
  __shared__ float s_zf[SF];
  __shared__ float s_sigf[SF];
  __shared__ float s_wf[SF];
  __shared__ float s_rgb[SF][3];
  __shared__ float s_red[SF];

  // ---- ray setup (uniform across block; compiler scalarizes) ----
  const float k00 = K[0], k01 = K[1], k02 = K[2];
  const float k10 = K[3], k11 = K[4], k12 = K[5];
  const float k20 = K[6], k21 = K[7], k22 = K[8];
  const float det = k00 * (k11 * k22 - k12 * k21)
                  - k01 * (k10 * k22 - k12 * k20)
                  + k02 * (k10 * k21 - k11 * k20);
  const float id = 1.0f / det;
  const float i00 =  (k11 * k22 - k12 * k21) * id;
  const float i01 = -(k01 * k22 - k02 * k21) * id;
  const float i02 =  (k01 * k12 - k02 * k11) * id;
  const float i10 = -(k10 * k22 - k12 * k20) * id;
  const float i11 =  (k00 * k22 - k02 * k20) * id;
  const float i12 = -(k00 * k12 - k02 * k10) * id;
  const float i20 =  (k10 * k21 - k11 * k20) * id;
  const float i21 = -(k00 * k21 - k01 * k20) * id;
  const float i22 =  (k00 * k11 - k01 * k10) * id;

  const float dwx = ww[ray] + 0.5f;
  const float dwy = hh[ray] + 0.5f;
  const float cx = i00 * dwx + i01 * dwy + i02;
  const float cy = i10 * dwx + i11 * dwy + i12;
  const float cz = i20 * dwx + i21 * dwy + i22;
  const float* Er = E + (size_t)ray * 16;
  const float ox = Er[3], oy = Er[7], oz = Er[11];
  const float dx = Er[0] * cx + Er[1] * cy + Er[2] * cz;
  const float dy = Er[4] * cx + Er[5] * cy + Er[6] * cz;
  const float dz = Er[8] * cx + Er[9] * cy + Er[10] * cz;
  const float nrm = sqrtf(dx * dx + dy * dy + dz * dz);
  const float ndx = dx / nrm, ndy = dy / nrm, ndz = dz / nrm;

  // ---- coarse pass: one sample per thread ----
  {
    const float zl = zlog_c(t);
    const float z = exp10f(zl);
    float px = ox + dx * z, py = oy + dy * z, pz = oz + dz * z;
    const float dist = sqrtf(px * px + py * py + pz * pz);
    if (dist > 1.0f) {
      const float sc = (2.0f - 1.0f / dist) / dist;
      px *= sc; py *= sc; pz *= sc;
    }
    float hbuf[32];
    s_sig[t] = density_mlp(px, py, pz, Wd1, bd1, Wd2, bd2, hbuf);
  }
  __syncthreads();

  // transmittance scan (serial, exact cumprod semantics)
  if (t == 0) {
    float T = 1.0f;
    for (int i = 0; i < SC; ++i) {
      const float a = 1.0f - expf(-s_sig[i] * delta_c(i));
      s_w[i] = a * T;
      T *= (1.0f - a);
    }
  }
  __syncthreads();

  // reweight
  {
    const float wm  = (t > 0)      ? s_w[t - 1] : 0.0f;
    const float w0  = s_w[t];
    const float wpp = (t < SC - 1) ? s_w[t + 1] : 0.0f;
    float wv = 0.5f * (fmaxf(wm, w0) + fmaxf(w0, wpp)) + (0.02f / 192.0f);
    wv *= (t < 128) ? (128.0f / 192.0f) : (64.0f / 192.0f);
    s_wre[t] = wv;
  }
  __syncthreads();

  // normalize + cdf (serial)
  if (t == 0) {
    float tot = 0.0f;
    for (int i = 0; i < SC; ++i) tot += s_wre[i];
    float c = 0.0f;
    for (int i = 0; i < SC; ++i) {
      c += s_wre[i] / tot;
      s_cdf[i] = c;
    }
  }
  __syncthreads();

  // ---- importance sampling + fine pass ----
  if (t < SF) {
    // JAX uniform bits: iota split into halves, threefry per pair
    const uint32_t total = (uint32_t)n_rays * 128u;
    const uint32_t halfc = total >> 1;
    const uint32_t j = (uint32_t)ray * 128u + (uint32_t)t;
    uint32_t x0, x1;
    const bool first = (j < halfc);
    if (first) { x0 = j; x1 = j + halfc; } else { x0 = j - halfc; x1 = j; }
    threefry2x32_k42(x0, x1);
    const uint32_t bits = first ? x0 : x1;
    const float fr = __uint_as_float((bits >> 9) | 0x3f800000u) - 1.0f;

    float u = (float)t * 0.0078125f + fr * 0.0078125f;
    u = u * (s_cdf[190] - s_cdf[1]) + s_cdf[1];

    // searchsorted(cdf[1:190], u, side='right') + 1
    int lo = 0, hi = 189;
    while (lo < hi) {
      const int mid = (lo + hi) >> 1;
      if (s_cdf[1 + mid] <= u) lo = mid + 1; else hi = mid;
    }
    const int inds = lo + 1;  // in [1, 190]
    const float cb = s_cdf[inds - 1], ca = s_cdf[inds];
    const float tt = (u - cb) / (ca - cb);
    const float zb = 0.5f * (zlog_c(inds - 1) + zlog_c(inds));
    const float za = 0.5f * (zlog_c(inds) + zlog_c(inds + 1));
    const float zlf = zb + (za - zb) * tt;
    s_zlf[t] = zlf;
    const float zf = exp10f(zlf);
    s_zf[t] = zf;

    float px = ox + dx * zf, py = oy + dy * zf, pz = oz + dz * zf;
    const float dist = sqrtf(px * px + py * py + pz * pz);
    if (dist > 1.0f) {
      const float sc = (2.0f - 1.0f / dist) / dist;
      px *= sc; py *= sc; pz *= sc;
    }
    float hfeat[32];
    s_sigf[t] = density_mlp(px, py, pz, Wd1, bd1, Wd2, bd2, hfeat);

    // color MLP: relu([hfeat, ndir] @ Wc1 + bc1) @ Wc2 + bc2 -> sigmoid
    float a1[32];
#pragma unroll
    for (int k = 0; k < 32; ++k) a1[k] = bc1[k];
#pragma unroll
    for (int i = 0; i < 32; ++i) {
      const float hv = hfeat[i];
#pragma unroll
      for (int k = 0; k < 32; ++k) a1[k] += hv * Wc1[i * 32 + k];
    }
#pragma unroll
    for (int k = 0; k < 32; ++k) {
      float acc = a1[k] + ndx * Wc1[32 * 32 + k]
                        + ndy * Wc1[33 * 32 + k]
                        + ndz * Wc1[34 * 32 + k];
      a1[k] = fmaxf(acc, 0.0f);
    }
#pragma unroll
    for (int c = 0; c < 3; ++c) {
      float acc = bc2[c];
#pragma unroll
      for (int k = 0; k < 32; ++k) acc += a1[k] * Wc2[k * 3 + c];
      s_rgb[t][c] = 1.0f / (1.0f + expf(-acc));
    }
  }
  __syncthreads();

  // fine transmittance scan
  if (t == 0) {
    float T = 1.0f;
    for (int i = 0; i < SF; ++i) {
      const float delta = (i < SF - 1) ? (s_zlf[i + 1] - s_zlf[i]) : 0.0f;
      const float a = 1.0f - expf(-s_sigf[i] * delta);
      s_wf[i] = a * T;
      T *= (1.0f - a);
    }
  }
  __syncthreads();

  // reductions: image(3), acc_weight, invdepth — reuse coarse arrays as scratch
  if (t < SF) {
    const float wv = s_wf[t];
    s_sig[t] = wv * s_rgb[t][0];
    s_w[t]   = wv * s_rgb[t][1];
    s_wre[t] = wv * s_rgb[t][2];
    s_cdf[t] = wv;
    s_red[t] = wv / s_zf[t];
  }
  for (int str = 64; str > 0; str >>= 1) {
    __syncthreads();
    if (t < str) {
      s_sig[t] += s_sig[t + str];
      s_w[t]   += s_w[t + str];
      s_wre[t] += s_wre[t + str];
      s_cdf[t] += s_cdf[t + str];
      s_red[t] += s_red[t + str];
    }
  }
  __syncthreads();

  // ---- outputs (f32), concatenated: image | weights | z_log_s | invdepth ----
  float* o_img = out;
  float* o_w   = out + (size_t)n_rays * 3;
  float* o_z   = out + (size_t)n_rays * (3 + 128);
  float* o_inv = out + (size_t)n_rays * (3 + 256);

  if (t < SF) {
    o_w[(size_t)ray * 128 + t] = s_wf[t];
    o_z[(size_t)ray * 128 + t] = (s_zlf[t] + 1.0f) * 0.5f;
  }
  if (t == 0) {
    const float accw = s_cdf[0];
    o_img[(size_t)ray * 3 + 0] = s_sig[0] + (1.0f - accw) * bg[0];
    o_img[(size_t)ray * 3 + 1] = s_w[0]   + (1.0f - accw) * bg[1];
    o_img[(size_t)ray * 3 + 2] = s_wre[0] + (1.0f - accw) * bg[2];
    o_inv[ray] = s_red[0];
  }
}

extern "C" void kernel_launch(void* const* d_in, const int* in_sizes, int n_in,
                              void* d_out, int out_size, void* d_ws, size_t ws_size,
                              hipStream_t stream) {
  // setup_inputs order: n, h, w, K, E, bg_color, Wd1, bd1, Wd2, bd2, Wc1, bc1, Wc2, bc2
  const float* h   = (const float*)d_in[1];
  const float* w   = (const float*)d_in[2];
  const float* K   = (const float*)d_in[3];
  const float* E   = (const float*)d_in[4];
  const float* bg  = (const float*)d_in[5];
  const float* Wd1 = (const float*)d_in[6];
  const float* bd1 = (const float*)d_in[7];
  const float* Wd2 = (const float*)d_in[8];
  const float* bd2 = (const float*)d_in[9];
  const float* Wc1 = (const float*)d_in[10];
  const float* bc1 = (const float*)d_in[11];
  const float* Wc2 = (const float*)d_in[12];
  const float* bc2 = (const float*)d_in[13];
  const int n_rays = in_sizes[1];

  nerf_fwd<<<n_rays, NT, 0, stream>>>(h, w, K, E, bg, Wd1, bd1, Wd2, bd2,
                                      Wc1, bc1, Wc2, bc2,
                                      (float*)d_out, n_rays);
}

// Round 4
// 385.258 us; speedup vs baseline: 1.5673x; 1.5673x over previous
//
#include <hip/hip_runtime.h>
#include <stdint.h>

#define SC 192      // coarse samples (128 + 64)
#define SF 128      // fine (importance) samples
#define NT 128      // threads per block = 2 waves; fine pass uses ALL threads

// z_log coarse grid: seg0 linspace(-1,-1/128,128) step 1/128; seg1 linspace(0,1-1/64,64) step 1/64
__device__ __forceinline__ float zlog_c(int t) {
  return (t < 128) ? (-1.0f + (float)t * 0.0078125f)
                   : ((float)(t - 128) * 0.015625f);
}
__device__ __forceinline__ float delta_c(int t) {
  if (t >= SC - 1) return 0.0f;
  return zlog_c(t + 1) - zlog_c(t);
}

__device__ __forceinline__ float fast_rcp(float x) { return __builtin_amdgcn_rcpf(x); }
__device__ __forceinline__ float fast_rsq(float x) { return __builtin_amdgcn_rsqf(x); }
__device__ __forceinline__ float exp10_f(float x) { return __expf(x * 2.30258509299f); }

__device__ __forceinline__ float softplus_f(float x) {
  // max(x,0) + log1p(exp(-|x|)); __logf(1+e) abs-err <=~1e-7, fine at 0.06 tol
  return fmaxf(x, 0.0f) + __logf(1.0f + __expf(-fabsf(x)));
}

// JAX threefry2x32 with key = (0, 42)
__device__ __forceinline__ void threefry2x32_k42(uint32_t& x0, uint32_t& x1) {
  const uint32_t ks0 = 0u, ks1 = 42u;
  const uint32_t ks2 = ks0 ^ ks1 ^ 0x1BD11BDAu;
  const uint32_t ks[3] = {ks0, ks1, ks2};
  const int rot[2][4] = {{13, 15, 26, 6}, {17, 29, 16, 24}};
  x0 += ks[0];
  x1 += ks[1];
#pragma unroll
  for (int i = 0; i < 5; ++i) {
#pragma unroll
    for (int j = 0; j < 4; ++j) {
      x0 += x1;
      const int r = rot[i & 1][j];
      x1 = (x1 << r) | (x1 >> (32 - r));
      x1 ^= x0;
    }
    x0 += ks[(i + 1) % 3];
    x1 += ks[(i + 2) % 3] + (uint32_t)(i + 1);
  }
}

// wave-level inclusive scans (Hillis-Steele via shfl_up, 6 steps)
__device__ __forceinline__ float wave_scan_mul(float v, int lane) {
#pragma unroll
  for (int d = 1; d < 64; d <<= 1) {
    float o = __shfl_up(v, d, 64);
    if (lane >= d) v *= o;
  }
  return v;
}
__device__ __forceinline__ float wave_scan_add(float v, int lane) {
#pragma unroll
  for (int d = 1; d < 64; d <<= 1) {
    float o = __shfl_up(v, d, 64);
    if (lane >= d) v += o;
  }
  return v;
}

// density MLP, sigma only (coarse)
__device__ __forceinline__ float density_sigma(
    float px, float py, float pz,
    const float* __restrict__ Wd1, const float* __restrict__ bd1,
    const float* __restrict__ Wd2, const float* __restrict__ bd2) {
  float acc = bd2[0];
#pragma unroll
  for (int k = 0; k < 32; ++k) {
    float v = bd1[k] + px * Wd1[k] + py * Wd1[32 + k] + pz * Wd1[64 + k];
    acc += fmaxf(v, 0.0f) * Wd2[k];
  }
  return softplus_f(acc);
}

// density MLP with hidden features (fine)
__device__ __forceinline__ float density_full(
    float px, float py, float pz,
    const float* __restrict__ Wd1, const float* __restrict__ bd1,
    const float* __restrict__ Wd2, const float* __restrict__ bd2,
    float* hfeat) {
  float acc = bd2[0];
#pragma unroll
  for (int k = 0; k < 32; ++k) {
    float v = bd1[k] + px * Wd1[k] + py * Wd1[32 + k] + pz * Wd1[64 + k];
    v = fmaxf(v, 0.0f);
    hfeat[k] = v;
    acc += v * Wd2[k];
  }
  return softplus_f(acc);
}

__global__ __launch_bounds__(NT, 4) void nerf_fwd(
    const float* __restrict__ hh, const float* __restrict__ ww,
    const float* __restrict__ K, const float* __restrict__ E,
    const float* __restrict__ bg,
    const float* __restrict__ Wd1, const float* __restrict__ bd1,
    const float* __restrict__ Wd2, const float* __restrict__ bd2,
    const float* __restrict__ Wc1, const float* __restrict__ bc1,
    const float* __restrict__ Wc2, const float* __restrict__ bc2,
    float* __restrict__ out, int n_rays) {
  const int ray = blockIdx.x;
  const int t = threadIdx.x;
  const int lane = t & 63;
  const int wv = t >> 6;   // 0 or 1

  __shared__ float s_w[SC];     // coarse weights
  __shared__ float s_cdf[SC];   // coarse CDF
  __shared__ float s_zlf[SF];   // fine z_log
  __shared__ float s_tot[8];    // chunk totals (0..2 coarse prod / fine prod; 4..6 cdf sums)
  __shared__ float s_red[16];   // 2 waves x 5 partial sums

  // ---- ray setup (uniform across block) ----
  const float k00 = K[0], k01 = K[1], k02 = K[2];
  const float k10 = K[3], k11 = K[4], k12 = K[5];
  const float k20 = K[6], k21 = K[7], k22 = K[8];
  const float det = k00 * (k11 * k22 - k12 * k21)
                  - k01 * (k10 * k22 - k12 * k20)
                  + k02 * (k10 * k21 - k11 * k20);
  const float id = 1.0f / det;
  const float i00 =  (k11 * k22 - k12 * k21) * id;
  const float i01 = -(k01 * k22 - k02 * k21) * id;
  const float i02 =  (k01 * k12 - k02 * k11) * id;
  const float i10 = -(k10 * k22 - k12 * k20) * id;
  const float i11 =  (k00 * k22 - k02 * k20) * id;
  const float i12 = -(k00 * k12 - k02 * k10) * id;
  const float i20 =  (k10 * k21 - k11 * k20) * id;
  const float i21 = -(k00 * k21 - k01 * k20) * id;
  const float i22 =  (k00 * k11 - k01 * k10) * id;

  const float dwx = ww[ray] + 0.5f;
  const float dwy = hh[ray] + 0.5f;
  const float cx = i00 * dwx + i01 * dwy + i02;
  const float cy = i10 * dwx + i11 * dwy + i12;
  const float cz = i20 * dwx + i21 * dwy + i22;
  const float* Er = E + (size_t)ray * 16;
  const float ox = Er[3], oy = Er[7], oz = Er[11];
  const float dx = Er[0] * cx + Er[1] * cy + Er[2] * cz;
  const float dy = Er[4] * cx + Er[5] * cy + Er[6] * cz;
  const float dz = Er[8] * cx + Er[9] * cy + Er[10] * cz;
  const float inv_nrm = fast_rsq(dx * dx + dy * dy + dz * dz);
  const float ndx = dx * inv_nrm, ndy = dy * inv_nrm, ndz = dz * inv_nrm;

  // ---- coarse pass: element e0 = t (all threads); e1 = 128+t (wave 0 only) ----
  float a0, v0, a1e = 0.0f, v1e = 1.0f;
  {
    const float z = exp10_f(zlog_c(t));
    float px = ox + dx * z, py = oy + dy * z, pz = oz + dz * z;
    const float dist = sqrtf(px * px + py * py + pz * pz);
    if (dist > 1.0f) {
      const float invd = fast_rcp(dist);
      const float sc = (2.0f - invd) * invd;
      px *= sc; py *= sc; pz *= sc;
    }
    const float sig = density_sigma(px, py, pz, Wd1, bd1, Wd2, bd2);
    v0 = __expf(-sig * delta_c(t));   // 1 - alpha
    a0 = 1.0f - v0;
  }
  if (wv == 0) {
    const int e = 128 + t;
    const float z = exp10_f(zlog_c(e));
    float px = ox + dx * z, py = oy + dy * z, pz = oz + dz * z;
    const float dist = sqrtf(px * px + py * py + pz * pz);
    if (dist > 1.0f) {
      const float invd = fast_rcp(dist);
      const float sc = (2.0f - invd) * invd;
      px *= sc; py *= sc; pz *= sc;
    }
    const float sig = density_sigma(px, py, pz, Wd1, bd1, Wd2, bd2);
    v1e = __expf(-sig * delta_c(e));
    a1e = 1.0f - v1e;
  }

  // parallel cumprod of (1-alpha): per-chunk shfl scans + LDS-chained totals
  float i0 = wave_scan_mul(v0, lane);               // wave0: chunk0, wave1: chunk1
  float i1 = 1.0f;
  if (wv == 0) i1 = wave_scan_mul(v1e, lane);       // chunk2
  if (lane == 63) s_tot[wv] = i0;
  if (wv == 0 && lane == 63) s_tot[2] = i1;
  __syncthreads();
  {
    const float preC1 = s_tot[0];
    const float preC2 = s_tot[0] * s_tot[1];
    float e0x = __shfl_up(i0, 1, 64); if (lane == 0) e0x = 1.0f;
    s_w[t] = a0 * e0x * (wv ? preC1 : 1.0f);
    if (wv == 0) {
      float e1x = __shfl_up(i1, 1, 64); if (lane == 0) e1x = 1.0f;
      s_w[128 + t] = a1e * e1x * preC2;
    }
  }
  __syncthreads();

  // reweight (elementwise, reads s_w neighbors)
  float wre0, wre1 = 0.0f;
  {
    const float wm = (t > 0) ? s_w[t - 1] : 0.0f;
    const float w0 = s_w[t];
    const float wp = s_w[t + 1];   // t<127 always valid; t=127 -> s_w[128] valid elem
    wre0 = 0.5f * (fmaxf(wm, w0) + fmaxf(w0, wp)) + (0.02f / 192.0f);
    wre0 *= (t < 128) ? (128.0f / 192.0f) : (64.0f / 192.0f);
  }
  if (wv == 0) {
    const int e = 128 + t;
    const float wm = s_w[e - 1];
    const float w0 = s_w[e];
    const float wp = (e < SC - 1) ? s_w[e + 1] : 0.0f;
    wre1 = 0.5f * (fmaxf(wm, w0) + fmaxf(w0, wp)) + (0.02f / 192.0f);
    wre1 *= (64.0f / 192.0f);
  }

  // parallel cumsum -> normalized CDF
  float s0 = wave_scan_add(wre0, lane);
  float s1 = 0.0f;
  if (wv == 0) s1 = wave_scan_add(wre1, lane);
  if (lane == 63) s_tot[4 + wv] = s0;
  if (wv == 0 && lane == 63) s_tot[6] = s1;
  __syncthreads();
  {
    const float T0 = s_tot[4], T1 = s_tot[5], T2 = s_tot[6];
    const float inv_total = fast_rcp(T0 + T1 + T2);
    s_cdf[t] = (s0 + (wv ? T0 : 0.0f)) * inv_total;
    if (wv == 0) s_cdf[128 + t] = (s1 + T0 + T1) * inv_total;
  }
  __syncthreads();

  // ---- importance sampling + fine pass (ALL 128 threads) ----
  float zlf, zf;
  {
    const uint32_t total = (uint32_t)n_rays * 128u;
    const uint32_t halfc = total >> 1;
    const uint32_t j = (uint32_t)ray * 128u + (uint32_t)t;
    uint32_t x0, x1;
    const bool first = (j < halfc);
    if (first) { x0 = j; x1 = j + halfc; } else { x0 = j - halfc; x1 = j; }
    threefry2x32_k42(x0, x1);
    const uint32_t bits = first ? x0 : x1;
    const float fr = __uint_as_float((bits >> 9) | 0x3f800000u) - 1.0f;

    float u = (float)t * 0.0078125f + fr * 0.0078125f;
    u = u * (s_cdf[190] - s_cdf[1]) + s_cdf[1];

    // searchsorted(cdf[1:190], u, side='right') + 1
    int lo = 0, hi = 189;
    while (lo < hi) {
      const int mid = (lo + hi) >> 1;
      if (s_cdf[1 + mid] <= u) lo = mid + 1; else hi = mid;
    }
    const int inds = lo + 1;  // [1, 190]
    const float cb = s_cdf[inds - 1], ca = s_cdf[inds];
    const float tt = (u - cb) * fast_rcp(ca - cb);
    const float zb = 0.5f * (zlog_c(inds - 1) + zlog_c(inds));
    const float za = 0.5f * (zlog_c(inds) + zlog_c(inds + 1));
    zlf = zb + (za - zb) * tt;
    s_zlf[t] = zlf;
    zf = exp10_f(zlf);
  }
  __syncthreads();

  float cr, cg, cbl, sigf;
  {
    float px = ox + dx * zf, py = oy + dy * zf, pz = oz + dz * zf;
    const float dist = sqrtf(px * px + py * py + pz * pz);
    if (dist > 1.0f) {
      const float invd = fast_rcp(dist);
      const float sc = (2.0f - invd) * invd;
      px *= sc; py *= sc; pz *= sc;
    }
    float hfeat[32];
    sigf = density_full(px, py, pz, Wd1, bd1, Wd2, bd2, hfeat);

    // color MLP: relu([hfeat, ndir] @ Wc1 + bc1) @ Wc2 + bc2 -> sigmoid
    float a1[32];
#pragma unroll
    for (int k = 0; k < 32; ++k) a1[k] = bc1[k];
#pragma unroll
    for (int i = 0; i < 32; ++i) {
      const float hv = hfeat[i];
#pragma unroll
      for (int k = 0; k < 32; ++k) a1[k] += hv * Wc1[i * 32 + k];
    }
#pragma unroll
    for (int k = 0; k < 32; ++k) {
      float acc = a1[k] + ndx * Wc1[32 * 32 + k]
                        + ndy * Wc1[33 * 32 + k]
                        + ndz * Wc1[34 * 32 + k];
      a1[k] = fmaxf(acc, 0.0f);
    }
    float o0 = bc2[0], o1 = bc2[1], o2 = bc2[2];
#pragma unroll
    for (int k = 0; k < 32; ++k) {
      o0 += a1[k] * Wc2[k * 3 + 0];
      o1 += a1[k] * Wc2[k * 3 + 1];
      o2 += a1[k] * Wc2[k * 3 + 2];
    }
    cr  = fast_rcp(1.0f + __expf(-o0));
    cg  = fast_rcp(1.0f + __expf(-o1));
    cbl = fast_rcp(1.0f + __expf(-o2));
  }

  // fine alpha + parallel cumprod over 128 (2 chunks of 64)
  const float deltaf = (t < SF - 1) ? (s_zlf[t + 1] - zlf) : 0.0f;
  const float vf = __expf(-sigf * deltaf);
  const float af = 1.0f - vf;
  float fi = wave_scan_mul(vf, lane);
  if (lane == 63) s_tot[wv] = fi;     // safe: s_tot[0..2] last read 2 barriers ago
  __syncthreads();
  float efx = __shfl_up(fi, 1, 64); if (lane == 0) efx = 1.0f;
  const float wf = af * efx * (wv ? s_tot[0] : 1.0f);

  // ---- outputs ----
  float* o_img = out;
  float* o_w   = out + (size_t)n_rays * 3;
  float* o_z   = out + (size_t)n_rays * (3 + 128);
  float* o_inv = out + (size_t)n_rays * (3 + 256);

  o_w[(size_t)ray * 128 + t] = wf;
  o_z[(size_t)ray * 128 + t] = (zlf + 1.0f) * 0.5f;

  // reductions: image rgb, acc weight, invdepth
  float r0 = wf * cr, r1 = wf * cg, r2 = wf * cbl, r3 = wf, r4 = wf * fast_rcp(zf);
#pragma unroll
  for (int d = 32; d > 0; d >>= 1) {
    r0 += __shfl_down(r0, d, 64);
    r1 += __shfl_down(r1, d, 64);
    r2 += __shfl_down(r2, d, 64);
    r3 += __shfl_down(r3, d, 64);
    r4 += __shfl_down(r4, d, 64);
  }
  if (lane == 0) {
    float* p = &s_red[wv * 5];
    p[0] = r0; p[1] = r1; p[2] = r2; p[3] = r3; p[4] = r4;
  }
  __syncthreads();
  if (t == 0) {
    const float accw = s_red[3] + s_red[8];
    const float bgw = 1.0f - accw;
    o_img[(size_t)ray * 3 + 0] = (s_red[0] + s_red[5]) + bgw * bg[0];
    o_img[(size_t)ray * 3 + 1] = (s_red[1] + s_red[6]) + bgw * bg[1];
    o_img[(size_t)ray * 3 + 2] = (s_red[2] + s_red[7]) + bgw * bg[2];
    o_inv[ray] = s_red[4] + s_red[9];
  }
}

extern "C" void kernel_launch(void* const* d_in, const int* in_sizes, int n_in,
                              void* d_out, int out_size, void* d_ws, size_t ws_size,
                              hipStream_t stream) {
  // setup_inputs order: n, h, w, K, E, bg_color, Wd1, bd1, Wd2, bd2, Wc1, bc1, Wc2, bc2
  const float* h   = (const float*)d_in[1];
  const float* w   = (const float*)d_in[2];
  const float* K   = (const float*)d_in[3];
  const float* E   = (const float*)d_in[4];
  const float* bg  = (const float*)d_in[5];
  const float* Wd1 = (const float*)d_in[6];
  const float* bd1 = (const float*)d_in[7];
  const float* Wd2 = (const float*)d_in[8];
  const float* bd2 = (const float*)d_in[9];
  const float* Wc1 = (const float*)d_in[10];
  const float* bc1 = (const float*)d_in[11];
  const float* Wc2 = (const float*)d_in[12];
  const float* bc2 = (const float*)d_in[13];
  const int n_rays = in_sizes[1];

  nerf_fwd<<<n_rays, NT, 0, stream>>>(h, w, K, E, bg, Wd1, bd1, Wd2, bd2,
                                      Wc1, bc1, Wc2, bc2,
                                      (float*)d_out, n_rays);
}

// Round 5
// 381.244 us; speedup vs baseline: 1.5838x; 1.0105x over previous
//
#include <hip/hip_runtime.h>
#include <stdint.h>

#define SC 192      // coarse samples (128 + 64)
#define SF 128      // fine (importance) samples
#define NT 128      // threads per block = 2 waves

typedef float f32x32 __attribute__((ext_vector_type(32)));

// z_log coarse grid: seg0 linspace(-1,-1/128,128) step 1/128; seg1 linspace(0,1-1/64,64) step 1/64
__device__ __forceinline__ float zlog_c(int t) {
  return (t < 128) ? (-1.0f + (float)t * 0.0078125f)
                   : ((float)(t - 128) * 0.015625f);
}
__device__ __forceinline__ float delta_c(int t) {
  if (t >= SC - 1) return 0.0f;
  return zlog_c(t + 1) - zlog_c(t);
}

__device__ __forceinline__ float fast_rcp(float x) { return __builtin_amdgcn_rcpf(x); }
__device__ __forceinline__ float fast_rsq(float x) { return __builtin_amdgcn_rsqf(x); }
__device__ __forceinline__ float exp10_f(float x) { return __expf(x * 2.30258509299f); }

__device__ __forceinline__ float softplus_f(float x) {
  return fmaxf(x, 0.0f) + __logf(1.0f + __expf(-fabsf(x)));
}

// JAX threefry2x32 with key = (0, 42)
__device__ __forceinline__ void threefry2x32_k42(uint32_t& x0, uint32_t& x1) {
  const uint32_t ks0 = 0u, ks1 = 42u;
  const uint32_t ks2 = ks0 ^ ks1 ^ 0x1BD11BDAu;
  const uint32_t ks[3] = {ks0, ks1, ks2};
  const int rot[2][4] = {{13, 15, 26, 6}, {17, 29, 16, 24}};
  x0 += ks[0];
  x1 += ks[1];
#pragma unroll
  for (int i = 0; i < 5; ++i) {
#pragma unroll
    for (int j = 0; j < 4; ++j) {
      x0 += x1;
      const int r = rot[i & 1][j];
      x1 = (x1 << r) | (x1 >> (32 - r));
      x1 ^= x0;
    }
    x0 += ks[(i + 1) % 3];
    x1 += ks[(i + 2) % 3] + (uint32_t)(i + 1);
  }
}

// wave-level inclusive scans (Hillis-Steele via shfl_up, 6 steps)
__device__ __forceinline__ float wave_scan_mul(float v, int lane) {
#pragma unroll
  for (int d = 1; d < 64; d <<= 1) {
    float o = __shfl_up(v, d, 64);
    if (lane >= d) v *= o;
  }
  return v;
}
__device__ __forceinline__ float wave_scan_add(float v, int lane) {
#pragma unroll
  for (int d = 1; d < 64; d <<= 1) {
    float o = __shfl_up(v, d, 64);
    if (lane >= d) v += o;
  }
  return v;
}

// density MLP, sigma only (coarse) — scalar accumulator, register-clean
__device__ __forceinline__ float density_sigma(
    float px, float py, float pz,
    const float* __restrict__ Wd1, const float* __restrict__ bd1,
    const float* __restrict__ Wd2, const float* __restrict__ bd2) {
  float acc = bd2[0];
#pragma unroll
  for (int k = 0; k < 32; ++k) {
    float v = bd1[k] + px * Wd1[k] + py * Wd1[32 + k] + pz * Wd1[64 + k];
    acc += fmaxf(v, 0.0f) * Wd2[k];
  }
  return softplus_f(acc);
}

__global__ __launch_bounds__(NT, 4) void nerf_fwd(
    const float* __restrict__ hh, const float* __restrict__ ww,
    const float* __restrict__ K, const float* __restrict__ E,
    const float* __restrict__ bg,
    const float* __restrict__ Wd1, const float* __restrict__ bd1,
    const float* __restrict__ Wd2, const float* __restrict__ bd2,
    const float* __restrict__ Wc1, const float* __restrict__ bc1,
    const float* __restrict__ Wc2, const float* __restrict__ bc2,
    float* __restrict__ out, int n_rays) {
  const int ray = blockIdx.x;
  const int t = threadIdx.x;
  const int lane = t & 63;
  const int wv = t >> 6;   // 0 or 1

  __shared__ float s_w[SC];     // coarse weights
  __shared__ float s_cdf[SC];   // coarse CDF
  __shared__ float s_zlf[SF];   // fine z_log
  __shared__ float s_tot[8];    // chunk totals
  __shared__ float s_red[16];   // 2 waves x 5 partial sums

  // ---- ray setup (block-uniform; compiler scalarizes) ----
  const float k00 = K[0], k01 = K[1], k02 = K[2];
  const float k10 = K[3], k11 = K[4], k12 = K[5];
  const float k20 = K[6], k21 = K[7], k22 = K[8];
  const float det = k00 * (k11 * k22 - k12 * k21)
                  - k01 * (k10 * k22 - k12 * k20)
                  + k02 * (k10 * k21 - k11 * k20);
  const float id = 1.0f / det;
  const float i00 =  (k11 * k22 - k12 * k21) * id;
  const float i01 = -(k01 * k22 - k02 * k21) * id;
  const float i02 =  (k01 * k12 - k02 * k11) * id;
  const float i10 = -(k10 * k22 - k12 * k20) * id;
  const float i11 =  (k00 * k22 - k02 * k20) * id;
  const float i12 = -(k00 * k12 - k02 * k10) * id;
  const float i20 =  (k10 * k21 - k11 * k20) * id;
  const float i21 = -(k00 * k21 - k01 * k20) * id;
  const float i22 =  (k00 * k11 - k01 * k10) * id;

  const float dwx = ww[ray] + 0.5f;
  const float dwy = hh[ray] + 0.5f;
  const float cx = i00 * dwx + i01 * dwy + i02;
  const float cy = i10 * dwx + i11 * dwy + i12;
  const float cz = i20 * dwx + i21 * dwy + i22;
  const float* Er = E + (size_t)ray * 16;
  const float ox = Er[3], oy = Er[7], oz = Er[11];
  const float dx = Er[0] * cx + Er[1] * cy + Er[2] * cz;
  const float dy = Er[4] * cx + Er[5] * cy + Er[6] * cz;
  const float dz = Er[8] * cx + Er[9] * cy + Er[10] * cz;
  const float inv_nrm = fast_rsq(dx * dx + dy * dy + dz * dz);
  const float ndx = dx * inv_nrm, ndy = dy * inv_nrm, ndz = dz * inv_nrm;

  // ---- coarse pass: element e0 = t (all threads); e1 = 128+t (wave 0 only) ----
  float a0, v0, a1e = 0.0f, v1e = 1.0f;
  {
    const float z = exp10_f(zlog_c(t));
    float px = ox + dx * z, py = oy + dy * z, pz = oz + dz * z;
    const float dist = sqrtf(px * px + py * py + pz * pz);
    if (dist > 1.0f) {
      const float invd = fast_rcp(dist);
      const float sc = (2.0f - invd) * invd;
      px *= sc; py *= sc; pz *= sc;
    }
    const float sig = density_sigma(px, py, pz, Wd1, bd1, Wd2, bd2);
    v0 = __expf(-sig * delta_c(t));   // 1 - alpha
    a0 = 1.0f - v0;
  }
  if (wv == 0) {
    const int e = 128 + t;
    const float z = exp10_f(zlog_c(e));
    float px = ox + dx * z, py = oy + dy * z, pz = oz + dz * z;
    const float dist = sqrtf(px * px + py * py + pz * pz);
    if (dist > 1.0f) {
      const float invd = fast_rcp(dist);
      const float sc = (2.0f - invd) * invd;
      px *= sc; py *= sc; pz *= sc;
    }
    const float sig = density_sigma(px, py, pz, Wd1, bd1, Wd2, bd2);
    v1e = __expf(-sig * delta_c(e));
    a1e = 1.0f - v1e;
  }

  // parallel cumprod of (1-alpha)
  float i0 = wave_scan_mul(v0, lane);
  float i1 = 1.0f;
  if (wv == 0) i1 = wave_scan_mul(v1e, lane);
  if (lane == 63) s_tot[wv] = i0;
  if (wv == 0 && lane == 63) s_tot[2] = i1;
  __syncthreads();
  {
    const float preC1 = s_tot[0];
    const float preC2 = s_tot[0] * s_tot[1];
    float e0x = __shfl_up(i0, 1, 64); if (lane == 0) e0x = 1.0f;
    s_w[t] = a0 * e0x * (wv ? preC1 : 1.0f);
    if (wv == 0) {
      float e1x = __shfl_up(i1, 1, 64); if (lane == 0) e1x = 1.0f;
      s_w[128 + t] = a1e * e1x * preC2;
    }
  }
  __syncthreads();

  // reweight
  float wre0, wre1 = 0.0f;
  {
    const float wm = (t > 0) ? s_w[t - 1] : 0.0f;
    const float w0 = s_w[t];
    const float wp = s_w[t + 1];
    wre0 = 0.5f * (fmaxf(wm, w0) + fmaxf(w0, wp)) + (0.02f / 192.0f);
    wre0 *= (t < 128) ? (128.0f / 192.0f) : (64.0f / 192.0f);
  }
  if (wv == 0) {
    const int e = 128 + t;
    const float wm = s_w[e - 1];
    const float w0 = s_w[e];
    const float wp = (e < SC - 1) ? s_w[e + 1] : 0.0f;
    wre1 = 0.5f * (fmaxf(wm, w0) + fmaxf(w0, wp)) + (0.02f / 192.0f);
    wre1 *= (64.0f / 192.0f);
  }

  // parallel cumsum -> normalized CDF
  float s0 = wave_scan_add(wre0, lane);
  float s1 = 0.0f;
  if (wv == 0) s1 = wave_scan_add(wre1, lane);
  if (lane == 63) s_tot[4 + wv] = s0;
  if (wv == 0 && lane == 63) s_tot[6] = s1;
  __syncthreads();
  {
    const float T0 = s_tot[4], T1 = s_tot[5], T2 = s_tot[6];
    const float inv_total = fast_rcp(T0 + T1 + T2);
    s_cdf[t] = (s0 + (wv ? T0 : 0.0f)) * inv_total;
    if (wv == 0) s_cdf[128 + t] = (s1 + T0 + T1) * inv_total;
  }
  __syncthreads();

  // ---- importance sampling (ALL 128 threads) ----
  float zlf, zf;
  {
    const uint32_t total = (uint32_t)n_rays * 128u;
    const uint32_t halfc = total >> 1;
    const uint32_t j = (uint32_t)ray * 128u + (uint32_t)t;
    uint32_t x0, x1;
    const bool first = (j < halfc);
    if (first) { x0 = j; x1 = j + halfc; } else { x0 = j - halfc; x1 = j; }
    threefry2x32_k42(x0, x1);
    const uint32_t bits = first ? x0 : x1;
    const float fr = __uint_as_float((bits >> 9) | 0x3f800000u) - 1.0f;

    float u = (float)t * 0.0078125f + fr * 0.0078125f;
    u = u * (s_cdf[190] - s_cdf[1]) + s_cdf[1];

    // searchsorted(cdf[1:190], u, side='right') + 1
    int lo = 0, hi = 189;
    while (lo < hi) {
      const int mid = (lo + hi) >> 1;
      if (s_cdf[1 + mid] <= u) lo = mid + 1; else hi = mid;
    }
    const int inds = lo + 1;  // [1, 190]
    const float cb = s_cdf[inds - 1], ca = s_cdf[inds];
    const float tt = (u - cb) * fast_rcp(ca - cb);
    const float zb = 0.5f * (zlog_c(inds - 1) + zlog_c(inds));
    const float za = 0.5f * (zlog_c(inds) + zlog_c(inds + 1));
    zlf = zb + (za - zb) * tt;
    s_zlf[t] = zlf;
    zf = exp10_f(zlf);
  }
  __syncthreads();

  // ---- fine pass: density + color MLP, arrays as ext-vectors (register-resident) ----
  float cr, cg, cbl, sigf;
  {
    float px = ox + dx * zf, py = oy + dy * zf, pz = oz + dz * zf;
    const float dist = sqrtf(px * px + py * py + pz * pz);
    if (dist > 1.0f) {
      const float invd = fast_rcp(dist);
      const float sc = (2.0f - invd) * invd;
      px *= sc; py *= sc; pz *= sc;
    }

    // density with hidden features
    f32x32 hfeat;
    {
      float acc = bd2[0];
#pragma unroll
      for (int k = 0; k < 32; ++k) {
        float v = bd1[k] + px * Wd1[k] + py * Wd1[32 + k] + pz * Wd1[64 + k];
        v = fmaxf(v, 0.0f);
        hfeat[k] = v;
        acc += v * Wd2[k];
      }
      sigf = softplus_f(acc);
    }

    // color MLP: relu([hfeat, ndir] @ Wc1 + bc1) @ Wc2 + bc2 -> sigmoid
    f32x32 a1;
#pragma unroll
    for (int k = 0; k < 32; ++k)
      a1[k] = bc1[k] + ndx * Wc1[32 * 32 + k]
                     + ndy * Wc1[33 * 32 + k]
                     + ndz * Wc1[34 * 32 + k];
#pragma unroll
    for (int i = 0; i < 32; ++i) {
      const float hv = hfeat[i];
#pragma unroll
      for (int k = 0; k < 32; ++k) a1[k] += hv * Wc1[i * 32 + k];
    }
    float o0 = bc2[0], o1 = bc2[1], o2 = bc2[2];
#pragma unroll
    for (int k = 0; k < 32; ++k) {
      const float av = fmaxf(a1[k], 0.0f);
      o0 += av * Wc2[k * 3 + 0];
      o1 += av * Wc2[k * 3 + 1];
      o2 += av * Wc2[k * 3 + 2];
    }
    cr  = fast_rcp(1.0f + __expf(-o0));
    cg  = fast_rcp(1.0f + __expf(-o1));
    cbl = fast_rcp(1.0f + __expf(-o2));
  }

  // fine alpha + parallel cumprod over 128 (2 chunks of 64)
  const float deltaf = (t < SF - 1) ? (s_zlf[t + 1] - zlf) : 0.0f;
  const float vf = __expf(-sigf * deltaf);
  const float af = 1.0f - vf;
  float fi = wave_scan_mul(vf, lane);
  if (lane == 63) s_tot[wv] = fi;
  __syncthreads();
  float efx = __shfl_up(fi, 1, 64); if (lane == 0) efx = 1.0f;
  const float wf = af * efx * (wv ? s_tot[0] : 1.0f);

  // ---- outputs ----
  float* o_img = out;
  float* o_w   = out + (size_t)n_rays * 3;
  float* o_z   = out + (size_t)n_rays * (3 + 128);
  float* o_inv = out + (size_t)n_rays * (3 + 256);

  o_w[(size_t)ray * 128 + t] = wf;
  o_z[(size_t)ray * 128 + t] = (zlf + 1.0f) * 0.5f;

  // reductions: image rgb, acc weight, invdepth
  float r0 = wf * cr, r1 = wf * cg, r2 = wf * cbl, r3 = wf, r4 = wf * fast_rcp(zf);
#pragma unroll
  for (int d = 32; d > 0; d >>= 1) {
    r0 += __shfl_down(r0, d, 64);
    r1 += __shfl_down(r1, d, 64);
    r2 += __shfl_down(r2, d, 64);
    r3 += __shfl_down(r3, d, 64);
    r4 += __shfl_down(r4, d, 64);
  }
  if (lane == 0) {
    float* p = &s_red[wv * 5];
    p[0] = r0; p[1] = r1; p[2] = r2; p[3] = r3; p[4] = r4;
  }
  __syncthreads();
  if (t == 0) {
    const float accw = s_red[3] + s_red[8];
    const float bgw = 1.0f - accw;
    o_img[(size_t)ray * 3 + 0] = (s_red[0] + s_red[5]) + bgw * bg[0];
    o_img[(size_t)ray * 3 + 1] = (s_red[1] + s_red[6]) + bgw * bg[1];
    o_img[(size_t)ray * 3 + 2] = (s_red[2] + s_red[7]) + bgw * bg[2];
    o_inv[ray] = s_red[4] + s_red[9];
  }
}

extern "C" void kernel_launch(void* const* d_in, const int* in_sizes, int n_in,
                              void* d_out, int out_size, void* d_ws, size_t ws_size,
                              hipStream_t stream) {
  // setup_inputs order: n, h, w, K, E, bg_color, Wd1, bd1, Wd2, bd2, Wc1, bc1, Wc2, bc2
  const float* h   = (const float*)d_in[1];
  const float* w   = (const float*)d_in[2];
  const float* K   = (const float*)d_in[3];
  const float* E   = (const float*)d_in[4];
  const float* bg  = (const float*)d_in[5];
  const float* Wd1 = (const float*)d_in[6];
  const float* bd1 = (const float*)d_in[7];
  const float* Wd2 = (const float*)d_in[8];
  const float* bd2 = (const float*)d_in[9];
  const float* Wc1 = (const float*)d_in[10];
  const float* bc1 = (const float*)d_in[11];
  const float* Wc2 = (const float*)d_in[12];
  const float* bc2 = (const float*)d_in[13];
  const int n_rays = in_sizes[1];

  nerf_fwd<<<n_rays, NT, 0, stream>>>(h, w, K, E, bg, Wd1, bd1, Wd2, bd2,
                                      Wc1, bc1, Wc2, bc2,
                                      (float*)d_out, n_rays);
}